// Round 1
// baseline (1550.856 us; speedup 1.0000x reference)
//
#include <hip/hip_runtime.h>

#define N_NODES 50000
#define N_EDGES 800000
#define IN_DIM  8
#define HD      128

// ---------------------------------------------------------------------------
// v3[j] = sum_k relu(W4[k]) * W3[k*HD + j]   (one tiny block)
// ---------------------------------------------------------------------------
__global__ void v3_kernel(const float* __restrict__ W4,
                          const float* __restrict__ W3,
                          float* __restrict__ v3) {
    int j = threadIdx.x;            // 0..127
    float acc = 0.f;
    for (int k = 0; k < HD; ++k) {
        float w = W4[k];
        w = w > 0.f ? w : 0.f;
        acc += w * W3[k * HD + j];
    }
    v3[j] = acc;
}

// ---------------------------------------------------------------------------
// S[row[e]] += edge_attr[e]   (scalar per-edge atomic)
// ---------------------------------------------------------------------------
__global__ void s_kernel(const int* __restrict__ ei,
                         const float* __restrict__ attr,
                         float* __restrict__ S) {
    int e = blockIdx.x * blockDim.x + threadIdx.x;
    if (e < N_EDGES) atomicAdd(&S[ei[e]], attr[e]);
}

// ---------------------------------------------------------------------------
// T = node_embedding @ W2   [N,128] @ [128,128], fp32 vector ALU.
// 128 threads (one per output column), 16 nodes per block staged in LDS.
// ---------------------------------------------------------------------------
__global__ void gemm_T(const float* __restrict__ emb,
                       const float* __restrict__ W2,
                       float* __restrict__ T) {
    const int NPB = 16;
    __shared__ float s_emb[NPB][HD];
    int j = threadIdx.x;                 // 0..127
    int base = blockIdx.x * NPB;
#pragma unroll
    for (int m = 0; m < NPB; ++m)
        s_emb[m][j] = emb[(base + m) * HD + j];
    __syncthreads();

    float acc[NPB];
#pragma unroll
    for (int m = 0; m < NPB; ++m) acc[m] = 0.f;

    for (int k = 0; k < HD; ++k) {
        float w = W2[k * HD + j];        // coalesced, L2-resident (64 KB)
#pragma unroll
        for (int m = 0; m < NPB; ++m)
            acc[m] += s_emb[m][k] * w;   // LDS broadcast read
    }
#pragma unroll
    for (int m = 0; m < NPB; ++m)
        T[(base + m) * HD + j] = acc[m];
}

// ---------------------------------------------------------------------------
// out[n][j] = x[n]@W1[:,j] + S[n]*v3[j]    (pre-scatter init, no relu yet)
// 256 threads = 2 nodes/block.
// ---------------------------------------------------------------------------
__global__ void init_out(const float* __restrict__ x,
                         const float* __restrict__ W1,
                         const float* __restrict__ S,
                         const float* __restrict__ v3,
                         float* __restrict__ out) {
    int tid  = blockIdx.x * 256 + threadIdx.x;
    int node = tid >> 7;
    int j    = tid & 127;
    if (node >= N_NODES) return;
    float acc = S[node] * v3[j];
#pragma unroll
    for (int i = 0; i < IN_DIM; ++i)
        acc += x[node * IN_DIM + i] * W1[i * HD + j];
    out[node * HD + j] = acc;
}

// ---------------------------------------------------------------------------
// out[row[e]] += T[col[e]]   — 32 threads/edge, float4 gather, 4 atomics each
// ---------------------------------------------------------------------------
__global__ void scatter_kernel(const int* __restrict__ ei,
                               const float* __restrict__ T,
                               float* __restrict__ out) {
    int tid  = blockIdx.x * 256 + threadIdx.x;
    int e    = tid >> 5;
    int lane = tid & 31;
    if (e >= N_EDGES) return;
    int row = ei[e];
    int col = ei[N_EDGES + e];
    float4 v = ((const float4*)(T + (size_t)col * HD))[lane];
    float* dst = out + (size_t)row * HD + lane * 4;
    atomicAdd(dst + 0, v.x);
    atomicAdd(dst + 1, v.y);
    atomicAdd(dst + 2, v.z);
    atomicAdd(dst + 3, v.w);
}

// ---------------------------------------------------------------------------
// out = max(out, 0)  (final relu), float4 grid-stride
// ---------------------------------------------------------------------------
__global__ void relu_kernel(float* __restrict__ out) {
    int i = blockIdx.x * 256 + threadIdx.x;   // exactly N_NODES*HD/4 threads
    float4* p = (float4*)out;
    float4 v = p[i];
    v.x = fmaxf(v.x, 0.f);
    v.y = fmaxf(v.y, 0.f);
    v.z = fmaxf(v.z, 0.f);
    v.w = fmaxf(v.w, 0.f);
    p[i] = v;
}

extern "C" void kernel_launch(void* const* d_in, const int* in_sizes, int n_in,
                              void* d_out, int out_size, void* d_ws, size_t ws_size,
                              hipStream_t stream) {
    const float* x    = (const float*)d_in[0];   // [N,8]
    const int*   ei   = (const int*)  d_in[1];   // [2,E] int32
    const float* attr = (const float*)d_in[2];   // [E,1]
    const float* emb  = (const float*)d_in[3];   // [N,128]
    const float* W1   = (const float*)d_in[4];   // [8,128]
    const float* W2   = (const float*)d_in[5];   // [128,128]
    const float* W3   = (const float*)d_in[6];   // [128,128]
    const float* W4   = (const float*)d_in[7];   // [1,128]
    float* out = (float*)d_out;                  // [N,128]

    // workspace layout: S (50000 f32) | v3 (128 f32) | T (50000*128 f32)
    float* S  = (float*)d_ws;
    float* v3 = S + N_NODES;                 // offset 200000 B (16B aligned)
    float* T  = v3 + HD;                     // offset 200512 B (16B aligned)

    hipMemsetAsync(S, 0, N_NODES * sizeof(float), stream);

    v3_kernel<<<1, HD, 0, stream>>>(W4, W3, v3);
    gemm_T<<<N_NODES / 16, HD, 0, stream>>>(emb, W2, T);
    s_kernel<<<N_EDGES / 256, 256, 0, stream>>>(ei, attr, S);
    init_out<<<N_NODES * HD / 256, 256, 0, stream>>>(x, W1, S, v3, out);
    scatter_kernel<<<(N_EDGES * 32) / 256, 256, 0, stream>>>(ei, T, out);
    relu_kernel<<<N_NODES * HD / 4 / 256, 256, 0, stream>>>(out);
}

// Round 2
// 341.457 us; speedup vs baseline: 4.5419x; 4.5419x over previous
//
#include <hip/hip_runtime.h>

#define N_NODES 50000
#define N_EDGES 800000
#define IN_DIM  8
#define HD      128
#define SCAN_CHUNK 1024
#define N_SCAN_BLOCKS ((N_NODES + SCAN_CHUNK - 1) / SCAN_CHUNK)   // 49

// ---------------------------------------------------------------------------
// v3[j] = sum_k relu(W4[k]) * W3[k*HD + j]
// (valid because edge_attr >= 0, so relu(a*w) = a*relu(w))
// ---------------------------------------------------------------------------
__global__ void v3_kernel(const float* __restrict__ W4,
                          const float* __restrict__ W3,
                          float* __restrict__ v3) {
    int j = threadIdx.x;            // 0..127
    float acc = 0.f;
    for (int k = 0; k < HD; ++k) {
        float w = W4[k];
        w = w > 0.f ? w : 0.f;
        acc += w * W3[k * HD + j];
    }
    v3[j] = acc;
}

// ---------------------------------------------------------------------------
// T = node_embedding @ W2   (segment_sum is linear: aggregate T rows instead)
// ---------------------------------------------------------------------------
__global__ void gemm_T(const float* __restrict__ emb,
                       const float* __restrict__ W2,
                       float* __restrict__ T) {
    const int NPB = 16;
    __shared__ float s_emb[NPB][HD];
    int j = threadIdx.x;                 // 0..127
    int base = blockIdx.x * NPB;
#pragma unroll
    for (int m = 0; m < NPB; ++m)
        s_emb[m][j] = emb[(base + m) * HD + j];
    __syncthreads();

    float acc[NPB];
#pragma unroll
    for (int m = 0; m < NPB; ++m) acc[m] = 0.f;

    for (int k = 0; k < HD; ++k) {
        float w = W2[k * HD + j];
#pragma unroll
        for (int m = 0; m < NPB; ++m)
            acc[m] += s_emb[m][k] * w;
    }
#pragma unroll
    for (int m = 0; m < NPB; ++m)
        T[(base + m) * HD + j] = acc[m];
}

// ---------------------------------------------------------------------------
// Per-edge: degree histogram + scalar edge_attr segment-sum (fused)
// ---------------------------------------------------------------------------
__global__ void hist_kernel(const int* __restrict__ ei,
                            const float* __restrict__ attr,
                            int* __restrict__ cnt,
                            float* __restrict__ S) {
    int e = blockIdx.x * 256 + threadIdx.x;
    if (e >= N_EDGES) return;
    int r = ei[e];
    atomicAdd(&cnt[r], 1);
    atomicAdd(&S[r], attr[e]);
}

// ---------------------------------------------------------------------------
// 3-pass exclusive scan of cnt[50000] -> offsets[50001]
// ---------------------------------------------------------------------------
__global__ void scan1_kernel(const int* __restrict__ cnt,
                             int* __restrict__ offsets,
                             int* __restrict__ blocksums) {
    __shared__ int lds[256];
    int t = threadIdx.x;
    int base = blockIdx.x * SCAN_CHUNK + t * 4;
    int v0 = 0, v1 = 0, v2 = 0, v3_ = 0;
    if (base + 0 < N_NODES) v0  = cnt[base + 0];
    if (base + 1 < N_NODES) v1  = cnt[base + 1];
    if (base + 2 < N_NODES) v2  = cnt[base + 2];
    if (base + 3 < N_NODES) v3_ = cnt[base + 3];
    int tsum = v0 + v1 + v2 + v3_;
    lds[t] = tsum;
    __syncthreads();
    for (int off = 1; off < 256; off <<= 1) {
        int add = (t >= off) ? lds[t - off] : 0;
        __syncthreads();
        lds[t] += add;
        __syncthreads();
    }
    int ex = lds[t] - tsum;              // exclusive prefix within block
    if (base + 0 < N_NODES) offsets[base + 0] = ex;
    if (base + 1 < N_NODES) offsets[base + 1] = ex + v0;
    if (base + 2 < N_NODES) offsets[base + 2] = ex + v0 + v1;
    if (base + 3 < N_NODES) offsets[base + 3] = ex + v0 + v1 + v2;
    if (t == 255) blocksums[blockIdx.x] = lds[255];
}

__global__ void scan2_kernel(int* __restrict__ blocksums,
                             int* __restrict__ offsets) {
    if (threadIdx.x == 0) {
        int run = 0;
        for (int i = 0; i < N_SCAN_BLOCKS; ++i) {
            int v = blocksums[i];
            blocksums[i] = run;
            run += v;
        }
        offsets[N_NODES] = run;          // == N_EDGES
    }
}

__global__ void scan3_kernel(int* __restrict__ offsets,
                             const int* __restrict__ blocksums,
                             int* __restrict__ cursor) {
    int t = threadIdx.x;
    int base = blockIdx.x * SCAN_CHUNK + t * 4;
    int add = blocksums[blockIdx.x];
#pragma unroll
    for (int i = 0; i < 4; ++i) {
        int idx = base + i;
        if (idx < N_NODES) {
            int o = offsets[idx] + add;
            offsets[idx] = o;
            cursor[idx] = o;             // cursor copy for fill_kernel
        }
    }
}

// ---------------------------------------------------------------------------
// Bucket edges by destination row: col_sorted[offsets[r] ...] = cols of r
// ---------------------------------------------------------------------------
__global__ void fill_kernel(const int* __restrict__ ei,
                            int* __restrict__ cursor,
                            int* __restrict__ col_sorted) {
    int e = blockIdx.x * 256 + threadIdx.x;
    if (e >= N_EDGES) return;
    int r = ei[e];
    int pos = atomicAdd(&cursor[r], 1);
    col_sorted[pos] = ei[N_EDGES + e];
}

// ---------------------------------------------------------------------------
// Owner-computes: out[n] = relu( x[n]@W1 + sum_{c in nbr(n)} T[c] + S[n]*v3 )
// 32 lanes per node, float4 per lane (512 B coalesced row reads, no atomics).
// ---------------------------------------------------------------------------
__global__ void aggregate_kernel(const int* __restrict__ offsets,
                                 const int* __restrict__ col_sorted,
                                 const float* __restrict__ T,
                                 const float* __restrict__ x,
                                 const float* __restrict__ W1,
                                 const float* __restrict__ S,
                                 const float* __restrict__ v3,
                                 float* __restrict__ out) {
    int tid  = blockIdx.x * 256 + threadIdx.x;
    int node = tid >> 5;                 // 8 nodes per block
    int lane = tid & 31;                 // owns columns [4*lane, 4*lane+4)
    if (node >= N_NODES) return;
    int start = offsets[node];
    int end   = offsets[node + 1];
    float4 acc = make_float4(0.f, 0.f, 0.f, 0.f);
    for (int e = start; e < end; ++e) {
        int c = col_sorted[e];           // broadcast within the 32-lane group
        float4 v = ((const float4*)(T + (size_t)c * HD))[lane];
        acc.x += v.x; acc.y += v.y; acc.z += v.z; acc.w += v.w;
    }
    float s = S[node];
    float4 b = ((const float4*)v3)[lane];
    acc.x += s * b.x; acc.y += s * b.y; acc.z += s * b.z; acc.w += s * b.w;
#pragma unroll
    for (int i = 0; i < IN_DIM; ++i) {
        float xi = x[node * IN_DIM + i];
        float4 w = ((const float4*)(W1 + i * HD))[lane];
        acc.x += xi * w.x; acc.y += xi * w.y; acc.z += xi * w.z; acc.w += xi * w.w;
    }
    acc.x = fmaxf(acc.x, 0.f);
    acc.y = fmaxf(acc.y, 0.f);
    acc.z = fmaxf(acc.z, 0.f);
    acc.w = fmaxf(acc.w, 0.f);
    ((float4*)(out + (size_t)node * HD))[lane] = acc;
}

extern "C" void kernel_launch(void* const* d_in, const int* in_sizes, int n_in,
                              void* d_out, int out_size, void* d_ws, size_t ws_size,
                              hipStream_t stream) {
    const float* x    = (const float*)d_in[0];   // [N,8]
    const int*   ei   = (const int*)  d_in[1];   // [2,E]
    const float* attr = (const float*)d_in[2];   // [E,1]
    const float* emb  = (const float*)d_in[3];   // [N,128]
    const float* W1   = (const float*)d_in[4];   // [8,128]
    const float* W2   = (const float*)d_in[5];   // [128,128]
    const float* W3   = (const float*)d_in[6];   // [128,128]
    const float* W4   = (const float*)d_in[7];   // [1,128]
    float* out = (float*)d_out;                  // [N,128]

    // workspace layout (29.4 MB total)
    float* S          = (float*)d_ws;            // 50000 f32
    float* v3         = S + N_NODES;             // 128 f32   (16B-aligned)
    float* T          = v3 + HD;                 // 6.4M f32  (16B-aligned)
    int*   cnt        = (int*)(T + (size_t)N_NODES * HD);  // 50000 (also cursor)
    int*   offsets    = cnt + N_NODES;           // 50001
    int*   blocksums  = offsets + N_NODES + 1;   // 64
    int*   col_sorted = blocksums + 64;          // 800000

    hipMemsetAsync(S,   0, N_NODES * sizeof(float), stream);
    hipMemsetAsync(cnt, 0, N_NODES * sizeof(int),   stream);

    v3_kernel <<<1, HD, 0, stream>>>(W4, W3, v3);
    gemm_T    <<<N_NODES / 16, HD, 0, stream>>>(emb, W2, T);
    hist_kernel<<<N_EDGES / 256, 256, 0, stream>>>(ei, attr, cnt, S);
    scan1_kernel<<<N_SCAN_BLOCKS, 256, 0, stream>>>(cnt, offsets, blocksums);
    scan2_kernel<<<1, 64, 0, stream>>>(blocksums, offsets);
    scan3_kernel<<<N_SCAN_BLOCKS, 256, 0, stream>>>(offsets, blocksums, cnt);
    fill_kernel <<<N_EDGES / 256, 256, 0, stream>>>(ei, cnt, col_sorted);
    aggregate_kernel<<<(N_NODES * 32) / 256, 256, 0, stream>>>(
        offsets, col_sorted, T, x, W1, S, v3, out);
}

// Round 3
// 290.535 us; speedup vs baseline: 5.3379x; 1.1753x over previous
//
#include <hip/hip_runtime.h>

#define N_NODES 50000
#define N_EDGES 800000
#define IN_DIM  8
#define HD      128
#define N_SCAN_BLOCKS ((N_NODES + 255) / 256)   // 196
#define NREP 4

typedef unsigned short ushort_t;

static __device__ inline unsigned short f2bf(float f) {   // fp32 -> bf16 RNE
    unsigned u = __float_as_uint(f);
    unsigned r = (u + 0x7FFF + ((u >> 16) & 1)) >> 16;
    return (unsigned short)r;
}
static __device__ inline float bf2f(unsigned short b) {
    return __uint_as_float(((unsigned)b) << 16);
}

// ---------------------------------------------------------------------------
// v3[j] = sum_k relu(W4[k]) * W3[k*HD + j]
// (valid because edge_attr >= 0, so relu(a*w) = a*relu(w))
// ---------------------------------------------------------------------------
__global__ void v3_kernel(const float* __restrict__ W4,
                          const float* __restrict__ W3,
                          float* __restrict__ v3) {
    int j = threadIdx.x;
    float acc = 0.f;
    for (int k = 0; k < HD; ++k) {
        float w = W4[k];
        w = w > 0.f ? w : 0.f;
        acc += w * W3[k * HD + j];
    }
    v3[j] = acc;
}

// ---------------------------------------------------------------------------
// T16 = bf16( node_embedding @ W2 ).  128 threads (one per col), 16 nodes/blk.
// emb reads are block-uniform -> scalar loads; no LDS.
// ---------------------------------------------------------------------------
__global__ void gemm_T(const float* __restrict__ emb,
                       const float* __restrict__ W2,
                       ushort_t* __restrict__ T16) {
    const int NPB = 16;
    int j = threadIdx.x;                 // 0..127
    int base = blockIdx.x * NPB;

    float acc[NPB];
#pragma unroll
    for (int m = 0; m < NPB; ++m) acc[m] = 0.f;

    for (int kg = 0; kg < HD / 4; ++kg) {
        int k = kg * 4;
        float w0 = W2[(k + 0) * HD + j];
        float w1 = W2[(k + 1) * HD + j];
        float w2 = W2[(k + 2) * HD + j];
        float w3 = W2[(k + 3) * HD + j];
#pragma unroll
        for (int m = 0; m < NPB; ++m) {
            float4 ev = ((const float4*)(emb + (size_t)(base + m) * HD))[kg];
            acc[m] += ev.x * w0 + ev.y * w1 + ev.z * w2 + ev.w * w3;
        }
    }
#pragma unroll
    for (int m = 0; m < NPB; ++m)
        T16[(size_t)(base + m) * HD + j] = f2bf(acc[m]);
}

// ---------------------------------------------------------------------------
// Pass 1: rank-capturing histogram with 4-way replicated counters.
// rep = blockIdx & 3 ; rank[e] = old value of cnt[rep][row[e]].
// ---------------------------------------------------------------------------
__global__ void hist_kernel(const int* __restrict__ ei,
                            int* __restrict__ cnt,
                            ushort_t* __restrict__ rank16) {
    int e = blockIdx.x * 256 + threadIdx.x;        // grid exactly covers E
    int rep = blockIdx.x & (NREP - 1);
    int r = ei[e];
    int rank = atomicAdd(&cnt[rep * N_NODES + r], 1);
    rank16[e] = (ushort_t)rank;
}

// ---------------------------------------------------------------------------
// Scan: per-node total = sum over reps; block scan -> off[] plus per-rep bases
// ---------------------------------------------------------------------------
__global__ void scan1_kernel(const int* __restrict__ cnt,
                             int* __restrict__ off,
                             int* __restrict__ b1, int* __restrict__ b2,
                             int* __restrict__ b3,
                             int* __restrict__ blocksums) {
    __shared__ int lds[256];
    int t = threadIdx.x;
    int n = blockIdx.x * 256 + t;
    int c0 = 0, c1 = 0, c2 = 0, c3 = 0;
    if (n < N_NODES) {
        c0 = cnt[0 * N_NODES + n];
        c1 = cnt[1 * N_NODES + n];
        c2 = cnt[2 * N_NODES + n];
        c3 = cnt[3 * N_NODES + n];
    }
    int tsum = c0 + c1 + c2 + c3;
    lds[t] = tsum;
    __syncthreads();
    for (int o = 1; o < 256; o <<= 1) {
        int add = (t >= o) ? lds[t - o] : 0;
        __syncthreads();
        lds[t] += add;
        __syncthreads();
    }
    int ex = lds[t] - tsum;              // exclusive prefix within block
    if (n < N_NODES) {
        off[n] = ex;
        b1[n]  = ex + c0;
        b2[n]  = ex + c0 + c1;
        b3[n]  = ex + c0 + c1 + c2;
    }
    if (t == 255) blocksums[blockIdx.x] = lds[255];
}

__global__ void scan2_kernel(int* __restrict__ blocksums,
                             int* __restrict__ off) {
    if (threadIdx.x == 0) {
        int run = 0;
        for (int i = 0; i < N_SCAN_BLOCKS; ++i) {
            int v = blocksums[i];
            blocksums[i] = run;
            run += v;
        }
        off[N_NODES] = run;              // == N_EDGES
    }
}

__global__ void scan3_kernel(int* __restrict__ off,
                             int* __restrict__ b1, int* __restrict__ b2,
                             int* __restrict__ b3,
                             const int* __restrict__ blocksums) {
    int t = threadIdx.x;
    int n = blockIdx.x * 256 + t;
    if (n >= N_NODES) return;
    int add = blocksums[blockIdx.x];
    off[n] += add;
    b1[n]  += add;
    b2[n]  += add;
    b3[n]  += add;
}

// ---------------------------------------------------------------------------
// Pass 2: place (col, attr) pairs -- NO atomics (position = base + rank)
// ---------------------------------------------------------------------------
__global__ void fill_kernel(const int* __restrict__ ei,
                            const float* __restrict__ attr,
                            const ushort_t* __restrict__ rank16,
                            const int* __restrict__ off,
                            const int* __restrict__ b1,
                            const int* __restrict__ b2,
                            const int* __restrict__ b3,
                            int2* __restrict__ col_attr) {
    int e = blockIdx.x * 256 + threadIdx.x;
    int rep = (e >> 8) & (NREP - 1);     // same mapping as hist_kernel
    int r = ei[e];
    int base = (rep == 0) ? off[r] : (rep == 1) ? b1[r] : (rep == 2) ? b2[r] : b3[r];
    int pos = base + (int)rank16[e];
    int2 p;
    p.x = ei[N_EDGES + e];
    p.y = __float_as_int(attr[e]);
    col_attr[pos] = p;
}

// ---------------------------------------------------------------------------
// Owner-computes: out[n] = relu( x[n]@W1 + sum_c T16[c] + (sum attr)*v3 )
// 32 lanes per node, bf16x4 (8 B) per lane per neighbor row -- no atomics.
// ---------------------------------------------------------------------------
__global__ void aggregate_kernel(const int* __restrict__ off,
                                 const int2* __restrict__ col_attr,
                                 const ushort_t* __restrict__ T16,
                                 const float* __restrict__ x,
                                 const float* __restrict__ W1,
                                 const float* __restrict__ v3,
                                 float* __restrict__ out) {
    int tid  = blockIdx.x * 256 + threadIdx.x;
    int node = tid >> 5;                 // 8 nodes per block
    int lane = tid & 31;                 // owns cols [4*lane, 4*lane+4)
    int s   = off[node];
    int e1  = off[node + 1];
    float4 acc = make_float4(0.f, 0.f, 0.f, 0.f);
    float ssum = 0.f;
    for (int e = s; e < e1; ++e) {
        int2 p = col_attr[e];            // broadcast within half-wave
        ssum += __int_as_float(p.y);
        const ushort4 tv = ((const ushort4*)(T16 + (size_t)p.x * HD))[lane];
        acc.x += bf2f(tv.x);
        acc.y += bf2f(tv.y);
        acc.z += bf2f(tv.z);
        acc.w += bf2f(tv.w);
    }
    float4 b = ((const float4*)v3)[lane];
    acc.x += ssum * b.x; acc.y += ssum * b.y;
    acc.z += ssum * b.z; acc.w += ssum * b.w;
#pragma unroll
    for (int i = 0; i < IN_DIM; ++i) {
        float xi = x[node * IN_DIM + i];
        float4 w = ((const float4*)(W1 + i * HD))[lane];
        acc.x += xi * w.x; acc.y += xi * w.y;
        acc.z += xi * w.z; acc.w += xi * w.w;
    }
    acc.x = fmaxf(acc.x, 0.f);
    acc.y = fmaxf(acc.y, 0.f);
    acc.z = fmaxf(acc.z, 0.f);
    acc.w = fmaxf(acc.w, 0.f);
    ((float4*)(out + (size_t)node * HD))[lane] = acc;
}

extern "C" void kernel_launch(void* const* d_in, const int* in_sizes, int n_in,
                              void* d_out, int out_size, void* d_ws, size_t ws_size,
                              hipStream_t stream) {
    const float* x    = (const float*)d_in[0];   // [N,8]
    const int*   ei   = (const int*)  d_in[1];   // [2,E]
    const float* attr = (const float*)d_in[2];   // [E,1]
    const float* emb  = (const float*)d_in[3];   // [N,128]
    const float* W1   = (const float*)d_in[4];   // [8,128]
    const float* W2   = (const float*)d_in[5];   // [128,128]
    const float* W3   = (const float*)d_in[6];   // [128,128]
    const float* W4   = (const float*)d_in[7];   // [1,128]
    float* out = (float*)d_out;                  // [N,128]

    // workspace layout (~22.4 MB)
    char* w = (char*)d_ws;
    int2*     col_attr = (int2*)w;                                   // 6.4 MB
    ushort_t* T16      = (ushort_t*)(w + (size_t)N_EDGES * 8);       // 12.8 MB
    int*      off      = (int*)(w + (size_t)N_EDGES * 8 + (size_t)N_NODES * HD * 2);
    int*      b1       = off + N_NODES + 1;
    int*      b2       = b1 + N_NODES;
    int*      b3       = b2 + N_NODES;
    int*      cnt      = b3 + N_NODES;           // NREP * N_NODES
    int*      bsums    = cnt + NREP * N_NODES;   // 256
    float*    v3       = (float*)(bsums + 256);  // 128
    ushort_t* rank16   = (ushort_t*)(v3 + HD);   // 1.6 MB

    hipMemsetAsync(cnt, 0, (size_t)NREP * N_NODES * sizeof(int), stream);

    v3_kernel   <<<1, HD, 0, stream>>>(W4, W3, v3);
    gemm_T      <<<N_NODES / 16, HD, 0, stream>>>(emb, W2, T16);
    hist_kernel <<<N_EDGES / 256, 256, 0, stream>>>(ei, cnt, rank16);
    scan1_kernel<<<N_SCAN_BLOCKS, 256, 0, stream>>>(cnt, off, b1, b2, b3, bsums);
    scan2_kernel<<<1, 64, 0, stream>>>(bsums, off);
    scan3_kernel<<<N_SCAN_BLOCKS, 256, 0, stream>>>(off, b1, b2, b3, bsums);
    fill_kernel <<<N_EDGES / 256, 256, 0, stream>>>(ei, attr, rank16, off, b1, b2, b3, col_attr);
    aggregate_kernel<<<(N_NODES * 32) / 256, 256, 0, stream>>>(
        off, col_attr, T16, x, W1, v3, out);
}

// Round 4
// 233.095 us; speedup vs baseline: 6.6533x; 1.2464x over previous
//
#include <hip/hip_runtime.h>

#define N_NODES 50000
#define N_EDGES 800000
#define IN_DIM  8
#define HD      128
#define N_SCAN_BLOCKS ((N_NODES + 255) / 256)   // 196
#define NREP 4
#define NTILES ((N_NODES + 63) / 64)            // 782 row-tiles of 64

typedef unsigned short ushort_t;
typedef __attribute__((ext_vector_type(8))) short short8;
typedef __attribute__((ext_vector_type(4))) float float4v;

static __device__ inline unsigned short f2bf(float f) {   // fp32 -> bf16 RNE
    unsigned u = __float_as_uint(f);
    unsigned r = (u + 0x7FFF + ((u >> 16) & 1)) >> 16;
    return (unsigned short)r;
}
static __device__ inline float bf2f(unsigned short b) {
    return __uint_as_float(((unsigned)b) << 16);
}

// ---------------------------------------------------------------------------
// v3[j] = sum_k relu(W4[k]) * W3[k*HD + j]
// (valid because edge_attr >= 0, so relu(a*w) = a*relu(w))
// ---------------------------------------------------------------------------
__global__ void v3_kernel(const float* __restrict__ W4,
                          const float* __restrict__ W3,
                          float* __restrict__ v3) {
    int j = threadIdx.x;
    float acc = 0.f;
    for (int k = 0; k < HD; ++k) {
        float w = W4[k];
        w = w > 0.f ? w : 0.f;
        acc += w * W3[k * HD + j];
    }
    v3[j] = acc;
}

// ---------------------------------------------------------------------------
// T16 = bf16( emb @ W2 ) via MFMA 16x16x32 bf16.
// 4 waves/block; wave computes 16 rows x 128 cols; B (all of W2, bf16)
// preloaded in 128 VGPRs per wave, amortized over grid-stride row-tiles.
// A loads: per-lane 32 B contiguous from own emb row (true vector loads).
// ---------------------------------------------------------------------------
__global__ __launch_bounds__(256, 2)
void gemm_T_mfma(const float* __restrict__ emb,
                 const float* __restrict__ W2,
                 ushort_t* __restrict__ T16) {
    int wave = threadIdx.x >> 6;        // 0..3
    int lane = threadIdx.x & 63;
    int n16  = lane & 15;               // col within a 16-wide tile
    int quad = lane >> 4;               // 0..3

    // B-frag[ct][ki] elem j = bf16(W2[(ki*32 + quad*8 + j)*HD + ct*16 + n16])
    short8 bfrag[8][4];
#pragma unroll
    for (int ct = 0; ct < 8; ++ct)
#pragma unroll
        for (int ki = 0; ki < 4; ++ki) {
            short8 f;
#pragma unroll
            for (int j = 0; j < 8; ++j) {
                int k = ki * 32 + quad * 8 + j;
                f[j] = (short)f2bf(W2[k * HD + ct * 16 + n16]);
            }
            bfrag[ct][ki] = f;
        }

    for (int tt = blockIdx.x; tt < NTILES; tt += gridDim.x) {
        int rowbase = tt * 64 + wave * 16;
        int row  = rowbase + n16;
        int rowc = row < N_NODES ? row : N_NODES - 1;
        const float4* arow = (const float4*)(emb + (size_t)rowc * HD);

        short8 afrag[4];
#pragma unroll
        for (int ki = 0; ki < 4; ++ki) {
            float4 lo = arow[ki * 8 + quad * 2];
            float4 hi = arow[ki * 8 + quad * 2 + 1];
            short8 a;
            a[0] = (short)f2bf(lo.x); a[1] = (short)f2bf(lo.y);
            a[2] = (short)f2bf(lo.z); a[3] = (short)f2bf(lo.w);
            a[4] = (short)f2bf(hi.x); a[5] = (short)f2bf(hi.y);
            a[6] = (short)f2bf(hi.z); a[7] = (short)f2bf(hi.w);
            afrag[ki] = a;
        }

        float4v acc[8];
#pragma unroll
        for (int ct = 0; ct < 8; ++ct) acc[ct] = (float4v){0.f, 0.f, 0.f, 0.f};

#pragma unroll
        for (int ki = 0; ki < 4; ++ki)
#pragma unroll
            for (int ct = 0; ct < 8; ++ct)
                acc[ct] = __builtin_amdgcn_mfma_f32_16x16x32_bf16(
                    afrag[ki], bfrag[ct][ki], acc[ct], 0, 0, 0);

        // C/D layout: col = lane&15 (within tile), row = quad*4 + reg
#pragma unroll
        for (int reg = 0; reg < 4; ++reg) {
            int r = rowbase + quad * 4 + reg;
            if (r < N_NODES) {
#pragma unroll
                for (int ct = 0; ct < 8; ++ct)
                    T16[(size_t)r * HD + ct * 16 + n16] = f2bf(acc[ct][reg]);
            }
        }
    }
}

// ---------------------------------------------------------------------------
// Pass 1: rank-capturing histogram with 4-way replicated counters.
// ---------------------------------------------------------------------------
__global__ void hist_kernel(const int* __restrict__ ei,
                            int* __restrict__ cnt,
                            ushort_t* __restrict__ rank16) {
    int e = blockIdx.x * 256 + threadIdx.x;        // grid exactly covers E
    int rep = blockIdx.x & (NREP - 1);
    int r = ei[e];
    int rank = atomicAdd(&cnt[rep * N_NODES + r], 1);
    rank16[e] = (ushort_t)rank;
}

// ---------------------------------------------------------------------------
// Scan: per-node total = sum over reps; block scan -> off[] plus per-rep bases
// ---------------------------------------------------------------------------
__global__ void scan1_kernel(const int* __restrict__ cnt,
                             int* __restrict__ off,
                             int* __restrict__ b1, int* __restrict__ b2,
                             int* __restrict__ b3,
                             int* __restrict__ blocksums) {
    __shared__ int lds[256];
    int t = threadIdx.x;
    int n = blockIdx.x * 256 + t;
    int c0 = 0, c1 = 0, c2 = 0, c3 = 0;
    if (n < N_NODES) {
        c0 = cnt[0 * N_NODES + n];
        c1 = cnt[1 * N_NODES + n];
        c2 = cnt[2 * N_NODES + n];
        c3 = cnt[3 * N_NODES + n];
    }
    int tsum = c0 + c1 + c2 + c3;
    lds[t] = tsum;
    __syncthreads();
    for (int o = 1; o < 256; o <<= 1) {
        int add = (t >= o) ? lds[t - o] : 0;
        __syncthreads();
        lds[t] += add;
        __syncthreads();
    }
    int ex = lds[t] - tsum;              // exclusive prefix within block
    if (n < N_NODES) {
        off[n] = ex;
        b1[n]  = ex + c0;
        b2[n]  = ex + c0 + c1;
        b3[n]  = ex + c0 + c1 + c2;
    }
    if (t == 255) blocksums[blockIdx.x] = lds[255];
}

__global__ void scan2_kernel(int* __restrict__ blocksums,
                             int* __restrict__ off) {
    __shared__ int lds[256];
    int t = threadIdx.x;
    int v = (t < N_SCAN_BLOCKS) ? blocksums[t] : 0;
    lds[t] = v;
    __syncthreads();
    for (int o = 1; o < 256; o <<= 1) {
        int add = (t >= o) ? lds[t - o] : 0;
        __syncthreads();
        lds[t] += add;
        __syncthreads();
    }
    if (t < N_SCAN_BLOCKS) blocksums[t] = lds[t] - v;   // exclusive
    if (t == 255) off[N_NODES] = lds[255];              // == N_EDGES
}

__global__ void scan3_kernel(int* __restrict__ off,
                             int* __restrict__ b1, int* __restrict__ b2,
                             int* __restrict__ b3,
                             const int* __restrict__ blocksums) {
    int t = threadIdx.x;
    int n = blockIdx.x * 256 + t;
    if (n >= N_NODES) return;
    int add = blocksums[blockIdx.x];
    off[n] += add;
    b1[n]  += add;
    b2[n]  += add;
    b3[n]  += add;
}

// ---------------------------------------------------------------------------
// Pass 2: place (col, attr) pairs -- NO atomics (position = base + rank)
// ---------------------------------------------------------------------------
__global__ void fill_kernel(const int* __restrict__ ei,
                            const float* __restrict__ attr,
                            const ushort_t* __restrict__ rank16,
                            const int* __restrict__ off,
                            const int* __restrict__ b1,
                            const int* __restrict__ b2,
                            const int* __restrict__ b3,
                            int2* __restrict__ col_attr) {
    int e = blockIdx.x * 256 + threadIdx.x;
    int rep = (e >> 8) & (NREP - 1);     // same mapping as hist_kernel
    int r = ei[e];
    int base = (rep == 0) ? off[r] : (rep == 1) ? b1[r] : (rep == 2) ? b2[r] : b3[r];
    int pos = base + (int)rank16[e];
    int2 p;
    p.x = ei[N_EDGES + e];
    p.y = __float_as_int(attr[e]);
    col_attr[pos] = p;
}

// ---------------------------------------------------------------------------
// Owner-computes: out[n] = relu( x[n]@W1 + sum_c T16[c] + (sum attr)*v3 )
// ---------------------------------------------------------------------------
__global__ void aggregate_kernel(const int* __restrict__ off,
                                 const int2* __restrict__ col_attr,
                                 const ushort_t* __restrict__ T16,
                                 const float* __restrict__ x,
                                 const float* __restrict__ W1,
                                 const float* __restrict__ v3,
                                 float* __restrict__ out) {
    int tid  = blockIdx.x * 256 + threadIdx.x;
    int node = tid >> 5;                 // 8 nodes per block
    int lane = tid & 31;                 // owns cols [4*lane, 4*lane+4)
    int s   = off[node];
    int e1  = off[node + 1];
    float4 acc = make_float4(0.f, 0.f, 0.f, 0.f);
    float ssum = 0.f;
    for (int e = s; e < e1; ++e) {
        int2 p = col_attr[e];            // broadcast within half-wave
        ssum += __int_as_float(p.y);
        const ushort4 tv = ((const ushort4*)(T16 + (size_t)p.x * HD))[lane];
        acc.x += bf2f(tv.x);
        acc.y += bf2f(tv.y);
        acc.z += bf2f(tv.z);
        acc.w += bf2f(tv.w);
    }
    float4 b = ((const float4*)v3)[lane];
    acc.x += ssum * b.x; acc.y += ssum * b.y;
    acc.z += ssum * b.z; acc.w += ssum * b.w;
#pragma unroll
    for (int i = 0; i < IN_DIM; ++i) {
        float xi = x[node * IN_DIM + i];
        float4 w = ((const float4*)(W1 + i * HD))[lane];
        acc.x += xi * w.x; acc.y += xi * w.y;
        acc.z += xi * w.z; acc.w += xi * w.w;
    }
    acc.x = fmaxf(acc.x, 0.f);
    acc.y = fmaxf(acc.y, 0.f);
    acc.z = fmaxf(acc.z, 0.f);
    acc.w = fmaxf(acc.w, 0.f);
    ((float4*)(out + (size_t)node * HD))[lane] = acc;
}

extern "C" void kernel_launch(void* const* d_in, const int* in_sizes, int n_in,
                              void* d_out, int out_size, void* d_ws, size_t ws_size,
                              hipStream_t stream) {
    const float* x    = (const float*)d_in[0];   // [N,8]
    const int*   ei   = (const int*)  d_in[1];   // [2,E]
    const float* attr = (const float*)d_in[2];   // [E,1]
    const float* emb  = (const float*)d_in[3];   // [N,128]
    const float* W1   = (const float*)d_in[4];   // [8,128]
    const float* W2   = (const float*)d_in[5];   // [128,128]
    const float* W3   = (const float*)d_in[6];   // [128,128]
    const float* W4   = (const float*)d_in[7];   // [1,128]
    float* out = (float*)d_out;                  // [N,128]

    // workspace layout (~22.4 MB)
    char* w = (char*)d_ws;
    int2*     col_attr = (int2*)w;                                   // 6.4 MB
    ushort_t* T16      = (ushort_t*)(w + (size_t)N_EDGES * 8);       // 12.8 MB
    int*      off      = (int*)(w + (size_t)N_EDGES * 8 + (size_t)N_NODES * HD * 2);
    int*      b1       = off + N_NODES + 1;
    int*      b2       = b1 + N_NODES;
    int*      b3       = b2 + N_NODES;
    int*      cnt      = b3 + N_NODES;           // NREP * N_NODES
    int*      bsums    = cnt + NREP * N_NODES;   // 256
    float*    v3       = (float*)(bsums + 256);  // 128
    ushort_t* rank16   = (ushort_t*)(v3 + HD);   // 1.6 MB

    hipMemsetAsync(cnt, 0, (size_t)NREP * N_NODES * sizeof(int), stream);

    v3_kernel   <<<1, HD, 0, stream>>>(W4, W3, v3);
    gemm_T_mfma <<<391, 256, 0, stream>>>(emb, W2, T16);
    hist_kernel <<<N_EDGES / 256, 256, 0, stream>>>(ei, cnt, rank16);
    scan1_kernel<<<N_SCAN_BLOCKS, 256, 0, stream>>>(cnt, off, b1, b2, b3, bsums);
    scan2_kernel<<<1, 256, 0, stream>>>(bsums, off);
    scan3_kernel<<<N_SCAN_BLOCKS, 256, 0, stream>>>(off, b1, b2, b3, bsums);
    fill_kernel <<<N_EDGES / 256, 256, 0, stream>>>(ei, attr, rank16, off, b1, b2, b3, col_attr);
    aggregate_kernel<<<(N_NODES * 32) / 256, 256, 0, stream>>>(
        off, col_attr, T16, x, W1, v3, out);
}

// Round 5
// 205.541 us; speedup vs baseline: 7.5452x; 1.1341x over previous
//
#include <hip/hip_runtime.h>

#define N_NODES 50000
#define N_EDGES 800000
#define IN_DIM  8
#define HD      128
#define N_SCAN_BLOCKS ((N_NODES + 255) / 256)   // 196
#define NREP 8
#define NTILES ((N_NODES + 63) / 64)            // 782 row-tiles of 64

typedef unsigned short ushort_t;
typedef __attribute__((ext_vector_type(8))) short short8;
typedef __attribute__((ext_vector_type(4))) float float4v;

static __device__ inline unsigned short f2bf(float f) {   // fp32 -> bf16 RNE
    unsigned u = __float_as_uint(f);
    unsigned r = (u + 0x7FFF + ((u >> 16) & 1)) >> 16;
    return (unsigned short)r;
}
static __device__ inline float bf2f(unsigned short b) {
    return __uint_as_float(((unsigned)b) << 16);
}

// ---------------------------------------------------------------------------
// v3[j] = sum_k relu(W4[k]) * W3[k*HD + j]
// (valid because edge_attr >= 0, so relu(a*w) = a*relu(w))
// ---------------------------------------------------------------------------
__global__ void v3_kernel(const float* __restrict__ W4,
                          const float* __restrict__ W3,
                          float* __restrict__ v3) {
    int j = threadIdx.x;
    float acc = 0.f;
    for (int k = 0; k < HD; ++k) {
        float w = W4[k];
        w = w > 0.f ? w : 0.f;
        acc += w * W3[k * HD + j];
    }
    v3[j] = acc;
}

// ---------------------------------------------------------------------------
// T16 = bf16( emb @ W2 ) via MFMA 16x16x32 bf16.
// B-fragments staged ONCE per block through LDS (frag-blob layout,
// sequential ds_read/write_b128, conflict-free), then held in VGPRs.
// ---------------------------------------------------------------------------
__global__ __launch_bounds__(256, 2)
void gemm_T_mfma(const float* __restrict__ emb,
                 const float* __restrict__ W2,
                 ushort_t* __restrict__ T16) {
    __shared__ short8 bshare[32][64];    // [frag ct*4+ki][lane], 32 KB
    int wave = threadIdx.x >> 6;        // 0..3
    int lane = threadIdx.x & 63;
    int n16  = lane & 15;               // col within a 16-wide tile
    int quad = lane >> 4;               // 0..3

    // Stage: wave w loads frags [w*8, w*8+8) -> 64 strided dword loads/wave
#pragma unroll
    for (int i = 0; i < 8; ++i) {
        int f  = wave * 8 + i;           // 0..31
        int ct = f >> 2, ki = f & 3;
        short8 fr;
#pragma unroll
        for (int j = 0; j < 8; ++j) {
            int k = ki * 32 + quad * 8 + j;
            fr[j] = (short)f2bf(W2[k * HD + ct * 16 + n16]);
        }
        bshare[f][lane] = fr;
    }
    __syncthreads();

    short8 bfrag[8][4];
#pragma unroll
    for (int ct = 0; ct < 8; ++ct)
#pragma unroll
        for (int ki = 0; ki < 4; ++ki)
            bfrag[ct][ki] = bshare[ct * 4 + ki][lane];

    for (int tt = blockIdx.x; tt < NTILES; tt += gridDim.x) {
        int rowbase = tt * 64 + wave * 16;
        int row  = rowbase + n16;
        int rowc = row < N_NODES ? row : N_NODES - 1;
        const float4* arow = (const float4*)(emb + (size_t)rowc * HD);

        short8 afrag[4];
#pragma unroll
        for (int ki = 0; ki < 4; ++ki) {
            float4 lo = arow[ki * 8 + quad * 2];
            float4 hi = arow[ki * 8 + quad * 2 + 1];
            short8 a;
            a[0] = (short)f2bf(lo.x); a[1] = (short)f2bf(lo.y);
            a[2] = (short)f2bf(lo.z); a[3] = (short)f2bf(lo.w);
            a[4] = (short)f2bf(hi.x); a[5] = (short)f2bf(hi.y);
            a[6] = (short)f2bf(hi.z); a[7] = (short)f2bf(hi.w);
            afrag[ki] = a;
        }

        float4v acc[8];
#pragma unroll
        for (int ct = 0; ct < 8; ++ct) acc[ct] = (float4v){0.f, 0.f, 0.f, 0.f};

#pragma unroll
        for (int ki = 0; ki < 4; ++ki)
#pragma unroll
            for (int ct = 0; ct < 8; ++ct)
                acc[ct] = __builtin_amdgcn_mfma_f32_16x16x32_bf16(
                    afrag[ki], bfrag[ct][ki], acc[ct], 0, 0, 0);

        // C/D layout: col = lane&15 (within tile), row = quad*4 + reg
#pragma unroll
        for (int reg = 0; reg < 4; ++reg) {
            int r = rowbase + quad * 4 + reg;
            if (r < N_NODES) {
#pragma unroll
                for (int ct = 0; ct < 8; ++ct)
                    T16[(size_t)r * HD + ct * 16 + n16] = f2bf(acc[ct][reg]);
            }
        }
    }
}

// ---------------------------------------------------------------------------
// Pass 1: rank-capturing histogram with 8-way replicated counters.
// ---------------------------------------------------------------------------
__global__ void hist_kernel(const int* __restrict__ ei,
                            int* __restrict__ cnt,
                            ushort_t* __restrict__ rank16) {
    int e = blockIdx.x * 256 + threadIdx.x;        // grid exactly covers E
    int rep = blockIdx.x & (NREP - 1);
    int r = ei[e];
    int rank = atomicAdd(&cnt[rep * N_NODES + r], 1);
    rank16[e] = (ushort_t)rank;
}

// ---------------------------------------------------------------------------
// Scan: per-node total over reps; block scan -> off[] + per-rep bases[]
// ---------------------------------------------------------------------------
__global__ void scan1_kernel(const int* __restrict__ cnt,
                             int* __restrict__ off,
                             int* __restrict__ bases,
                             int* __restrict__ blocksums) {
    __shared__ int lds[256];
    int t = threadIdx.x;
    int n = blockIdx.x * 256 + t;
    int c[NREP];
    int tsum = 0;
#pragma unroll
    for (int r = 0; r < NREP; ++r) {
        c[r] = (n < N_NODES) ? cnt[r * N_NODES + n] : 0;
        tsum += c[r];
    }
    lds[t] = tsum;
    __syncthreads();
    for (int o = 1; o < 256; o <<= 1) {
        int add = (t >= o) ? lds[t - o] : 0;
        __syncthreads();
        lds[t] += add;
        __syncthreads();
    }
    int ex = lds[t] - tsum;              // exclusive prefix within block
    if (n < N_NODES) {
        off[n] = ex;
        int run = ex;
#pragma unroll
        for (int r = 0; r < NREP; ++r) {
            bases[r * N_NODES + n] = run;
            run += c[r];
        }
    }
    if (t == 255) blocksums[blockIdx.x] = lds[255];
}

__global__ void scan2_kernel(int* __restrict__ blocksums,
                             int* __restrict__ off) {
    __shared__ int lds[256];
    int t = threadIdx.x;
    int v = (t < N_SCAN_BLOCKS) ? blocksums[t] : 0;
    lds[t] = v;
    __syncthreads();
    for (int o = 1; o < 256; o <<= 1) {
        int add = (t >= o) ? lds[t - o] : 0;
        __syncthreads();
        lds[t] += add;
        __syncthreads();
    }
    if (t < N_SCAN_BLOCKS) blocksums[t] = lds[t] - v;   // exclusive
    if (t == 255) off[N_NODES] = lds[255];              // == N_EDGES
}

__global__ void scan3_kernel(int* __restrict__ off,
                             int* __restrict__ bases,
                             const int* __restrict__ blocksums) {
    int t = threadIdx.x;
    int n = blockIdx.x * 256 + t;
    if (n >= N_NODES) return;
    int add = blocksums[blockIdx.x];
    off[n] += add;
#pragma unroll
    for (int r = 0; r < NREP; ++r)
        bases[r * N_NODES + n] += add;
}

// ---------------------------------------------------------------------------
// Pass 2: place (col, attr) pairs -- NO atomics (position = base + rank)
// ---------------------------------------------------------------------------
__global__ void fill_kernel(const int* __restrict__ ei,
                            const float* __restrict__ attr,
                            const ushort_t* __restrict__ rank16,
                            const int* __restrict__ bases,
                            int2* __restrict__ col_attr) {
    int e = blockIdx.x * 256 + threadIdx.x;
    int rep = (e >> 8) & (NREP - 1);     // same mapping as hist_kernel
    int r = ei[e];
    int pos = bases[rep * N_NODES + r] + (int)rank16[e];
    int2 p;
    p.x = ei[N_EDGES + e];
    p.y = __float_as_int(attr[e]);
    col_attr[pos] = p;
}

// ---------------------------------------------------------------------------
// Owner-computes: out[n] = relu( x[n]@W1 + sum_c T16[c] + (sum attr)*v3 )
// 32 lanes/node. Edge records loaded lane-parallel (one coalesced 256 B
// load per 32 edges), cols shfl-broadcast, gathers unrolled 4x for MLP.
// ---------------------------------------------------------------------------
__global__ void aggregate_kernel(const int* __restrict__ off,
                                 const int2* __restrict__ col_attr,
                                 const ushort_t* __restrict__ T16,
                                 const float* __restrict__ x,
                                 const float* __restrict__ W1,
                                 const float* __restrict__ v3,
                                 float* __restrict__ out) {
    int tid  = blockIdx.x * 256 + threadIdx.x;
    int node = tid >> 5;                 // 8 nodes per block
    int lane = tid & 31;                 // owns cols [4*lane, 4*lane+4)
    int s   = off[node];
    int deg = off[node + 1] - s;
    float4 acc = make_float4(0.f, 0.f, 0.f, 0.f);
    float ssum = 0.f;

    for (int base = 0; base < deg; base += 32) {
        int rem = deg - base; if (rem > 32) rem = 32;
        int2 p = make_int2(0, 0);
        if (lane < rem) p = col_attr[s + base + lane];
        ssum += __int_as_float(p.y);     // inactive lanes add +0.0f
        int j = 0;
        for (; j + 4 <= rem; j += 4) {
            int c0 = __shfl(p.x, j + 0, 32);
            int c1 = __shfl(p.x, j + 1, 32);
            int c2 = __shfl(p.x, j + 2, 32);
            int c3 = __shfl(p.x, j + 3, 32);
            ushort4 t0 = ((const ushort4*)(T16 + (size_t)c0 * HD))[lane];
            ushort4 t1 = ((const ushort4*)(T16 + (size_t)c1 * HD))[lane];
            ushort4 t2 = ((const ushort4*)(T16 + (size_t)c2 * HD))[lane];
            ushort4 t3 = ((const ushort4*)(T16 + (size_t)c3 * HD))[lane];
            acc.x += (bf2f(t0.x) + bf2f(t1.x)) + (bf2f(t2.x) + bf2f(t3.x));
            acc.y += (bf2f(t0.y) + bf2f(t1.y)) + (bf2f(t2.y) + bf2f(t3.y));
            acc.z += (bf2f(t0.z) + bf2f(t1.z)) + (bf2f(t2.z) + bf2f(t3.z));
            acc.w += (bf2f(t0.w) + bf2f(t1.w)) + (bf2f(t2.w) + bf2f(t3.w));
        }
        for (; j < rem; ++j) {
            int c = __shfl(p.x, j, 32);
            ushort4 t = ((const ushort4*)(T16 + (size_t)c * HD))[lane];
            acc.x += bf2f(t.x);
            acc.y += bf2f(t.y);
            acc.z += bf2f(t.z);
            acc.w += bf2f(t.w);
        }
    }
    // reduce ssum across the 32-lane group
    for (int o = 16; o; o >>= 1) ssum += __shfl_xor(ssum, o, 32);

    float4 b = ((const float4*)v3)[lane];
    acc.x += ssum * b.x; acc.y += ssum * b.y;
    acc.z += ssum * b.z; acc.w += ssum * b.w;
#pragma unroll
    for (int i = 0; i < IN_DIM; ++i) {
        float xi = x[node * IN_DIM + i];
        float4 w = ((const float4*)(W1 + i * HD))[lane];
        acc.x += xi * w.x; acc.y += xi * w.y;
        acc.z += xi * w.z; acc.w += xi * w.w;
    }
    acc.x = fmaxf(acc.x, 0.f);
    acc.y = fmaxf(acc.y, 0.f);
    acc.z = fmaxf(acc.z, 0.f);
    acc.w = fmaxf(acc.w, 0.f);
    ((float4*)(out + (size_t)node * HD))[lane] = acc;
}

extern "C" void kernel_launch(void* const* d_in, const int* in_sizes, int n_in,
                              void* d_out, int out_size, void* d_ws, size_t ws_size,
                              hipStream_t stream) {
    const float* x    = (const float*)d_in[0];   // [N,8]
    const int*   ei   = (const int*)  d_in[1];   // [2,E]
    const float* attr = (const float*)d_in[2];   // [E,1]
    const float* emb  = (const float*)d_in[3];   // [N,128]
    const float* W1   = (const float*)d_in[4];   // [8,128]
    const float* W2   = (const float*)d_in[5];   // [128,128]
    const float* W3   = (const float*)d_in[6];   // [128,128]
    const float* W4   = (const float*)d_in[7];   // [1,128]
    float* out = (float*)d_out;                  // [N,128]

    // workspace layout (~24.5 MB)
    char* w = (char*)d_ws;
    int2*     col_attr = (int2*)w;                                   // 6.4 MB
    ushort_t* T16      = (ushort_t*)(w + (size_t)N_EDGES * 8);       // 12.8 MB
    int*      off      = (int*)(w + (size_t)N_EDGES * 8 + (size_t)N_NODES * HD * 2);
    int*      bases    = off + N_NODES + 1;      // NREP * N_NODES
    int*      cnt      = bases + NREP * N_NODES; // NREP * N_NODES
    int*      bsums    = cnt + NREP * N_NODES;   // 256
    float*    v3       = (float*)(bsums + 256);  // 128
    ushort_t* rank16   = (ushort_t*)(v3 + HD);   // 1.6 MB

    hipMemsetAsync(cnt, 0, (size_t)NREP * N_NODES * sizeof(int), stream);

    v3_kernel   <<<1, HD, 0, stream>>>(W4, W3, v3);
    gemm_T_mfma <<<391, 256, 0, stream>>>(emb, W2, T16);
    hist_kernel <<<N_EDGES / 256, 256, 0, stream>>>(ei, cnt, rank16);
    scan1_kernel<<<N_SCAN_BLOCKS, 256, 0, stream>>>(cnt, off, bases, bsums);
    scan2_kernel<<<1, 256, 0, stream>>>(bsums, off);
    scan3_kernel<<<N_SCAN_BLOCKS, 256, 0, stream>>>(off, bases, bsums);
    fill_kernel <<<N_EDGES / 256, 256, 0, stream>>>(ei, attr, rank16, bases, col_attr);
    aggregate_kernel<<<(N_NODES * 32) / 256, 256, 0, stream>>>(
        off, col_attr, T16, x, W1, v3, out);
}

// Round 6
// 188.576 us; speedup vs baseline: 8.2240x; 1.0900x over previous
//
#include <hip/hip_runtime.h>

#define N_NODES 50000
#define N_EDGES 800000
#define IN_DIM  8
#define HD      128
#define N_SCAN_BLOCKS ((N_NODES + 255) / 256)   // 196
#define NREP 16
#define NTILES ((N_NODES + 63) / 64)            // 782 row-tiles of 64
#define N_HIST_BLOCKS (N_EDGES / 256)           // 3125
#define GRID_P1 (NTILES * 5)                    // 3910: 1 gemm per 4 hist

typedef unsigned short ushort_t;
typedef unsigned int uint_t;
typedef __attribute__((ext_vector_type(8))) short short8;
typedef __attribute__((ext_vector_type(4))) float float4v;

static __device__ inline unsigned short f2bf(float f) {   // fp32 -> bf16 RNE
    unsigned u = __float_as_uint(f);
    unsigned r = (u + 0x7FFF + ((u >> 16) & 1)) >> 16;
    return (unsigned short)r;
}
static __device__ inline float bf2f(unsigned short b) {
    return __uint_as_float(((unsigned)b) << 16);
}

// ---------------------------------------------------------------------------
// One-block prep: bf16 B-fragment blob for the MFMA gemm.
// blob[f=ct*4+ki][lane] elem j = bf16(W2[(ki*32+quad*8+j)*HD + ct*16 + n16])
// ---------------------------------------------------------------------------
__global__ void prep_kernel(const float* __restrict__ W2,
                            short8* __restrict__ blob) {
    int t = threadIdx.x;                 // 0..255
#pragma unroll
    for (int i = 0; i < 8; ++i) {
        int slot = t * 8 + i;            // 0..2047
        int f    = slot >> 6;            // 0..31
        int lane = slot & 63;
        int ct = f >> 2, ki = f & 3;
        int n16 = lane & 15, quad = lane >> 4;
        short8 fr;
#pragma unroll
        for (int j = 0; j < 8; ++j) {
            int k = ki * 32 + quad * 8 + j;
            fr[j] = (short)f2bf(W2[k * HD + ct * 16 + n16]);
        }
        blob[slot] = fr;
    }
}

// ---------------------------------------------------------------------------
// Fused phase 1: blockIdx%5==0 -> gemm tile (MFMA, BW-bound);
//                else          -> hist chunk (atomic-latency-bound).
// The two regimes co-schedule on each CU.
// ---------------------------------------------------------------------------
__global__ __launch_bounds__(256, 2)
void phase1_kernel(const float* __restrict__ emb,
                   const short8* __restrict__ blob,
                   ushort_t* __restrict__ T16,
                   const int* __restrict__ ei,
                   int* __restrict__ cnt,
                   ushort_t* __restrict__ rank16) {
    __shared__ short8 sblob[2048];       // 32 KB
    int sel = blockIdx.x % 5;

    if (sel != 0) {
        // ---- hist path: chunk c covers edges [c*256, c*256+256) ----
        int c = (blockIdx.x / 5) * 4 + sel - 1;
        if (c >= N_HIST_BLOCKS) return;
        int e = c * 256 + threadIdx.x;
        int rep = c & (NREP - 1);
        int r = ei[e];
        int rank = atomicAdd(&cnt[rep * N_NODES + r], 1);
        rank16[e] = (ushort_t)rank;
        return;
    }

    // ---- gemm path ----
    int tt   = blockIdx.x / 5;           // 0..781
    int t    = threadIdx.x;
    int wave = t >> 6;
    int lane = t & 63;
    int n16  = lane & 15;
    int quad = lane >> 4;

#pragma unroll
    for (int i = 0; i < 8; ++i)          // coalesced 32 KB copy
        sblob[t * 8 + i] = blob[t * 8 + i];
    __syncthreads();

    short8 bfrag[8][4];
#pragma unroll
    for (int ct = 0; ct < 8; ++ct)
#pragma unroll
        for (int ki = 0; ki < 4; ++ki)
            bfrag[ct][ki] = sblob[(ct * 4 + ki) * 64 + lane];

    int rowbase = tt * 64 + wave * 16;
    int row  = rowbase + n16;
    int rowc = row < N_NODES ? row : N_NODES - 1;
    const float4* arow = (const float4*)(emb + (size_t)rowc * HD);

    short8 afrag[4];
#pragma unroll
    for (int ki = 0; ki < 4; ++ki) {
        float4 lo = arow[ki * 8 + quad * 2];
        float4 hi = arow[ki * 8 + quad * 2 + 1];
        short8 a;
        a[0] = (short)f2bf(lo.x); a[1] = (short)f2bf(lo.y);
        a[2] = (short)f2bf(lo.z); a[3] = (short)f2bf(lo.w);
        a[4] = (short)f2bf(hi.x); a[5] = (short)f2bf(hi.y);
        a[6] = (short)f2bf(hi.z); a[7] = (short)f2bf(hi.w);
        afrag[ki] = a;
    }

    float4v acc[8];
#pragma unroll
    for (int ct = 0; ct < 8; ++ct) acc[ct] = (float4v){0.f, 0.f, 0.f, 0.f};

#pragma unroll
    for (int ki = 0; ki < 4; ++ki)
#pragma unroll
        for (int ct = 0; ct < 8; ++ct)
            acc[ct] = __builtin_amdgcn_mfma_f32_16x16x32_bf16(
                afrag[ki], bfrag[ct][ki], acc[ct], 0, 0, 0);

    // C/D layout: col = lane&15 (within tile), row = quad*4 + reg
#pragma unroll
    for (int reg = 0; reg < 4; ++reg) {
        int r = rowbase + quad * 4 + reg;
        if (r < N_NODES) {
#pragma unroll
            for (int ct = 0; ct < 8; ++ct)
                T16[(size_t)r * HD + ct * 16 + n16] = f2bf(acc[ct][reg]);
        }
    }
}

// ---------------------------------------------------------------------------
// Scan: per-node totals over reps; BLOCK-LOCAL exclusive off[] + bases[];
// global fixup (bsums) is applied by consumers on the fly (no scan3).
// ---------------------------------------------------------------------------
__global__ void scan1_kernel(const int* __restrict__ cnt,
                             int* __restrict__ off,
                             int* __restrict__ bases,
                             int* __restrict__ blocksums) {
    __shared__ int lds[256];
    int t = threadIdx.x;
    int n = blockIdx.x * 256 + t;
    int c[NREP];
    int tsum = 0;
#pragma unroll
    for (int r = 0; r < NREP; ++r) {
        c[r] = (n < N_NODES) ? cnt[r * N_NODES + n] : 0;
        tsum += c[r];
    }
    lds[t] = tsum;
    __syncthreads();
    for (int o = 1; o < 256; o <<= 1) {
        int add = (t >= o) ? lds[t - o] : 0;
        __syncthreads();
        lds[t] += add;
        __syncthreads();
    }
    int ex = lds[t] - tsum;              // exclusive prefix within block
    if (n < N_NODES) {
        off[n] = ex;
        int run = ex;
#pragma unroll
        for (int r = 0; r < NREP; ++r) {
            bases[r * N_NODES + n] = run;
            run += c[r];
        }
    }
    if (t == 255) blocksums[blockIdx.x] = lds[255];
}

// block 0: exclusive scan of blocksums; block 1: v3 = relu(W4) @ W3
__global__ void scan2_v3_kernel(int* __restrict__ blocksums,
                                const float* __restrict__ W4,
                                const float* __restrict__ W3,
                                float* __restrict__ v3) {
    int t = threadIdx.x;
    if (blockIdx.x == 1) {
        if (t < HD) {
            float acc = 0.f;
            for (int k = 0; k < HD; ++k) {
                float w = W4[k];
                w = w > 0.f ? w : 0.f;
                acc += w * W3[k * HD + t];
            }
            v3[t] = acc;
        }
        return;
    }
    __shared__ int lds[256];
    int v = (t < N_SCAN_BLOCKS) ? blocksums[t] : 0;
    lds[t] = v;
    __syncthreads();
    for (int o = 1; o < 256; o <<= 1) {
        int add = (t >= o) ? lds[t - o] : 0;
        __syncthreads();
        lds[t] += add;
        __syncthreads();
    }
    if (t < N_SCAN_BLOCKS) blocksums[t] = lds[t] - v;   // exclusive
}

// ---------------------------------------------------------------------------
// Pass 2: place packed (attr_bf16 << 16 | col) -- NO atomics.
// ---------------------------------------------------------------------------
__global__ void fill_kernel(const int* __restrict__ ei,
                            const float* __restrict__ attr,
                            const ushort_t* __restrict__ rank16,
                            const int* __restrict__ bases,
                            const int* __restrict__ bsums,
                            uint_t* __restrict__ packed) {
    int e = blockIdx.x * 256 + threadIdx.x;
    int rep = (e >> 8) & (NREP - 1);     // == chunk & (NREP-1), chunk = e>>8
    int r = ei[e];
    int pos = bases[rep * N_NODES + r] + bsums[r >> 8] + (int)rank16[e];
    uint_t p = ((uint_t)f2bf(attr[e]) << 16) | (uint_t)ei[N_EDGES + e];
    packed[pos] = p;
}

// ---------------------------------------------------------------------------
// Owner-computes: out[n] = relu( x[n]@W1 + sum_c T16[c] + (sum attr)*v3 )
// 16 lanes/node, ushort8 (16 B) per lane per neighbor row; MLP-4 gathers.
// ---------------------------------------------------------------------------
__global__ void aggregate_kernel(const int* __restrict__ off,
                                 const int* __restrict__ bsums,
                                 const uint_t* __restrict__ packed,
                                 const ushort_t* __restrict__ T16,
                                 const float* __restrict__ x,
                                 const float* __restrict__ W1,
                                 const float* __restrict__ v3,
                                 float* __restrict__ out) {
    int tid  = blockIdx.x * 256 + threadIdx.x;
    int node = tid >> 4;                 // 16 nodes per block
    int lane = tid & 15;                 // owns cols [8*lane, 8*lane+8)
    int s  = off[node] + bsums[node >> 8];
    int e1 = (node + 1 == N_NODES) ? N_EDGES
                                   : off[node + 1] + bsums[(node + 1) >> 8];
    int deg = e1 - s;

    float acc[8];
#pragma unroll
    for (int i = 0; i < 8; ++i) acc[i] = 0.f;
    float ssum = 0.f;

    for (int base = 0; base < deg; base += 16) {
        int rem = deg - base; if (rem > 16) rem = 16;
        uint_t p = 0;
        if (lane < rem) p = packed[s + base + lane];
        ssum += __uint_as_float(p & 0xFFFF0000u);    // attr (bf16 hi), +0 if idle
        int col = (int)(p & 0xFFFFu);
        int j = 0;
        for (; j + 4 <= rem; j += 4) {
            int c0 = __shfl(col, j + 0, 16);
            int c1 = __shfl(col, j + 1, 16);
            int c2 = __shfl(col, j + 2, 16);
            int c3 = __shfl(col, j + 3, 16);
            short8 t0 = ((const short8*)(T16 + (size_t)c0 * HD))[lane];
            short8 t1 = ((const short8*)(T16 + (size_t)c1 * HD))[lane];
            short8 t2 = ((const short8*)(T16 + (size_t)c2 * HD))[lane];
            short8 t3 = ((const short8*)(T16 + (size_t)c3 * HD))[lane];
#pragma unroll
            for (int i = 0; i < 8; ++i)
                acc[i] += (bf2f((ushort_t)t0[i]) + bf2f((ushort_t)t1[i]))
                        + (bf2f((ushort_t)t2[i]) + bf2f((ushort_t)t3[i]));
        }
        for (; j < rem; ++j) {
            int c = __shfl(col, j, 16);
            short8 tv = ((const short8*)(T16 + (size_t)c * HD))[lane];
#pragma unroll
            for (int i = 0; i < 8; ++i)
                acc[i] += bf2f((ushort_t)tv[i]);
        }
    }
    // reduce ssum across the 16-lane group
    for (int o = 8; o; o >>= 1) ssum += __shfl_xor(ssum, o, 16);

    const float4* v3p = (const float4*)v3;
    float4 b0 = v3p[lane * 2], b1 = v3p[lane * 2 + 1];
    acc[0] += ssum * b0.x; acc[1] += ssum * b0.y;
    acc[2] += ssum * b0.z; acc[3] += ssum * b0.w;
    acc[4] += ssum * b1.x; acc[5] += ssum * b1.y;
    acc[6] += ssum * b1.z; acc[7] += ssum * b1.w;
#pragma unroll
    for (int i = 0; i < IN_DIM; ++i) {
        float xi = x[node * IN_DIM + i];
        const float4* wp = (const float4*)(W1 + i * HD);
        float4 w0 = wp[lane * 2], w1 = wp[lane * 2 + 1];
        acc[0] += xi * w0.x; acc[1] += xi * w0.y;
        acc[2] += xi * w0.z; acc[3] += xi * w0.w;
        acc[4] += xi * w1.x; acc[5] += xi * w1.y;
        acc[6] += xi * w1.z; acc[7] += xi * w1.w;
    }
    float4 o0, o1;
    o0.x = fmaxf(acc[0], 0.f); o0.y = fmaxf(acc[1], 0.f);
    o0.z = fmaxf(acc[2], 0.f); o0.w = fmaxf(acc[3], 0.f);
    o1.x = fmaxf(acc[4], 0.f); o1.y = fmaxf(acc[5], 0.f);
    o1.z = fmaxf(acc[6], 0.f); o1.w = fmaxf(acc[7], 0.f);
    float4* op = (float4*)(out + (size_t)node * HD);
    op[lane * 2]     = o0;
    op[lane * 2 + 1] = o1;
}

extern "C" void kernel_launch(void* const* d_in, const int* in_sizes, int n_in,
                              void* d_out, int out_size, void* d_ws, size_t ws_size,
                              hipStream_t stream) {
    const float* x    = (const float*)d_in[0];   // [N,8]
    const int*   ei   = (const int*)  d_in[1];   // [2,E]
    const float* attr = (const float*)d_in[2];   // [E,1]
    const float* emb  = (const float*)d_in[3];   // [N,128]
    const float* W1   = (const float*)d_in[4];   // [8,128]
    const float* W2   = (const float*)d_in[5];   // [128,128]
    const float* W3   = (const float*)d_in[6];   // [128,128]
    const float* W4   = (const float*)d_in[7];   // [1,128]
    float* out = (float*)d_out;                  // [N,128]

    // workspace layout (~24.3 MB)
    char* w = (char*)d_ws;
    uint_t*   packed = (uint_t*)w;                                   // 3.2 MB
    ushort_t* T16    = (ushort_t*)(w + (size_t)N_EDGES * 4);         // 12.8 MB
    short8*   blob   = (short8*)((char*)T16 + (size_t)N_NODES * HD * 2); // 32 KB
    int*      off    = (int*)((char*)blob + 2048 * 16);              // N+4
    int*      bases  = off + N_NODES + 4;        // NREP * N_NODES   // 3.2 MB
    int*      cnt    = bases + NREP * N_NODES;   // NREP * N_NODES   // 3.2 MB
    int*      bsums  = cnt + NREP * N_NODES;     // 256
    float*    v3     = (float*)(bsums + 256);    // 128
    ushort_t* rank16 = (ushort_t*)(v3 + HD);     // 1.6 MB

    hipMemsetAsync(cnt, 0, (size_t)NREP * N_NODES * sizeof(int), stream);

    prep_kernel  <<<1, 256, 0, stream>>>(W2, blob);
    phase1_kernel<<<GRID_P1, 256, 0, stream>>>(emb, blob, T16, ei, cnt, rank16);
    scan1_kernel <<<N_SCAN_BLOCKS, 256, 0, stream>>>(cnt, off, bases, bsums);
    scan2_v3_kernel<<<2, 256, 0, stream>>>(bsums, W4, W3, v3);
    fill_kernel  <<<N_HIST_BLOCKS, 256, 0, stream>>>(ei, attr, rank16, bases, bsums, packed);
    aggregate_kernel<<<(N_NODES * 16) / 256, 256, 0, stream>>>(
        off, bsums, packed, T16, x, W1, v3, out);
}